// Round 7
// baseline (833.611 us; speedup 1.0000x reference)
//
#include <hip/hip_runtime.h>
#include <math.h>

#define ROWS 65536
#define DIM  256
#define KC   1024
#define NQ   (ROWS * DIM)

typedef float f2 __attribute__((ext_vector_type(2)));
typedef float f4v __attribute__((ext_vector_type(4)));
typedef short bf16x8 __attribute__((ext_vector_type(8)));
typedef float f32x4  __attribute__((ext_vector_type(4)));

// ---------------- fast-path ws layout (bytes) ----------------
// 0        double lossacc
// 16       int counts[1024]      -> 4112
// 4224     float B32[1024]       -> 8320
// 8320     int flagcnt           -> 8324   (memset covers 0..8336)
// 16384    int flaglist[65536]   -> 278528
// 278528   int idx32[65536]      -> 540672
// 540672   float Arr[65536]      -> 802816
// 802816   ushort Ehi[262144]    -> 1327104
// 1327104  ushort Elo[262144]    -> 1851392
#define WS_REQ 1851392
// out0 scratch during dist phase: Xhi ushort[NQ] at byte 0, Xlo at NQ*2.
// k_out overwrites out0 afterwards.

#define THRESH 4.0e-4f   // approx-gap below which row is exactly rechecked

// ---------------------------------------------------------------------------
// numpy pairwise sum-of-squares (identical op order to the passing kernel).
// ---------------------------------------------------------------------------
__device__ __forceinline__ float half_sq_sum(const float* __restrict__ a) {
    float4 u0 = *(const float4*)(a);
    float4 u1 = *(const float4*)(a + 4);
    float r0 = __fmul_rn(u0.x, u0.x);
    float r1 = __fmul_rn(u0.y, u0.y);
    float r2 = __fmul_rn(u0.z, u0.z);
    float r3 = __fmul_rn(u0.w, u0.w);
    float r4 = __fmul_rn(u1.x, u1.x);
    float r5 = __fmul_rn(u1.y, u1.y);
    float r6 = __fmul_rn(u1.z, u1.z);
    float r7 = __fmul_rn(u1.w, u1.w);
    for (int i = 8; i < 128; i += 8) {
        float4 v0 = *(const float4*)(a + i);
        float4 v1 = *(const float4*)(a + i + 4);
        r0 = __fadd_rn(r0, __fmul_rn(v0.x, v0.x));
        r1 = __fadd_rn(r1, __fmul_rn(v0.y, v0.y));
        r2 = __fadd_rn(r2, __fmul_rn(v0.z, v0.z));
        r3 = __fadd_rn(r3, __fmul_rn(v0.w, v0.w));
        r4 = __fadd_rn(r4, __fmul_rn(v1.x, v1.x));
        r5 = __fadd_rn(r5, __fmul_rn(v1.y, v1.y));
        r6 = __fadd_rn(r6, __fmul_rn(v1.z, v1.z));
        r7 = __fadd_rn(r7, __fmul_rn(v1.w, v1.w));
    }
    float s01 = __fadd_rn(r0, r1);
    float s23 = __fadd_rn(r2, r3);
    float s45 = __fadd_rn(r4, r5);
    float s67 = __fadd_rn(r6, r7);
    return __fadd_rn(__fadd_rn(s01, s23), __fadd_rn(s45, s67));
}

__device__ __forceinline__ float sq_sum_numpy(const float* __restrict__ p) {
    float h0 = half_sq_sum(p);
    float h1 = half_sq_sum(p + 128);
    return __fadd_rn(h0, h1);
}

__device__ __forceinline__ ushort bf16_rne(float f) {
    unsigned u = __float_as_uint(f);
    unsigned r = u + 0x7FFFu + ((u >> 16) & 1u);
    return (ushort)(r >> 16);
}
__device__ __forceinline__ float bf16_tof(ushort h) {
    return __uint_as_float(((unsigned)h) << 16);
}

// =================== FAST PATH ===================

// ---------------- P1: codebook norms + bf16 split --------------------------
__global__ __launch_bounds__(256) void k_prepE(const float* __restrict__ E,
                                               float* __restrict__ B32,
                                               ushort* __restrict__ Ehi,
                                               ushort* __restrict__ Elo) {
    int j = blockIdx.x * 256 + threadIdx.x;
    if (j >= KC) return;
    const float* p = E + (size_t)j * DIM;
    B32[j] = sq_sum_numpy(p);
    for (int d4 = 0; d4 < DIM; d4 += 4) {
        float4 v = *(const float4*)(p + d4);
        ushort h0 = bf16_rne(v.x), h1 = bf16_rne(v.y);
        ushort h2 = bf16_rne(v.z), h3 = bf16_rne(v.w);
        ushort l0 = bf16_rne(v.x - bf16_tof(h0));
        ushort l1 = bf16_rne(v.y - bf16_tof(h1));
        ushort l2 = bf16_rne(v.z - bf16_tof(h2));
        ushort l3 = bf16_rne(v.w - bf16_tof(h3));
        uint2 ph, pl;
        ph.x = (unsigned)h0 | ((unsigned)h1 << 16);
        ph.y = (unsigned)h2 | ((unsigned)h3 << 16);
        pl.x = (unsigned)l0 | ((unsigned)l1 << 16);
        pl.y = (unsigned)l2 | ((unsigned)l3 << 16);
        *(uint2*)(Ehi + (size_t)j * DIM + d4) = ph;
        *(uint2*)(Elo + (size_t)j * DIM + d4) = pl;
    }
}

// ---------------- P2: X bf16 split into out0 scratch -----------------------
__global__ __launch_bounds__(256) void k_prepX(const float* __restrict__ X,
                                               ushort* __restrict__ Xhi,
                                               ushort* __restrict__ Xlo) {
    size_t g = (size_t)(blockIdx.x * 256 + threadIdx.x) * 8;   // grid 8192 -> NQ
    float4 a = *(const float4*)(X + g);
    float4 b = *(const float4*)(X + g + 4);
    float f[8] = {a.x, a.y, a.z, a.w, b.x, b.y, b.z, b.w};
    ushort h[8], l[8];
#pragma unroll
    for (int i = 0; i < 8; ++i) {
        h[i] = bf16_rne(f[i]);
        l[i] = bf16_rne(f[i] - bf16_tof(h[i]));
    }
    uint4 ph, pl;
    ph.x = (unsigned)h[0] | ((unsigned)h[1] << 16);
    ph.y = (unsigned)h[2] | ((unsigned)h[3] << 16);
    ph.z = (unsigned)h[4] | ((unsigned)h[5] << 16);
    ph.w = (unsigned)h[6] | ((unsigned)h[7] << 16);
    pl.x = (unsigned)l[0] | ((unsigned)l[1] << 16);
    pl.y = (unsigned)l[2] | ((unsigned)l[3] << 16);
    pl.z = (unsigned)l[4] | ((unsigned)l[5] << 16);
    pl.w = (unsigned)l[6] | ((unsigned)l[7] << 16);
    *(uint4*)(Xhi + g) = ph;
    *(uint4*)(Xlo + g) = pl;
}

// ---------------- P3: MFMA distance + two-min argmin -----------------------
// 512 blocks x 256 thr (4 waves); tile 128 rows x 128 cols; K chunk 32.
// 3-term bf16 split GEMM: D = Xhi.Ehi + Xhi.Elo + Xlo.Ehi via
// mfma_f32_16x16x32_bf16 (A: row=l&15, k-quarter=l>>4; B: col=l&15;
// C: col=lane&15, row=(lane>>4)*4+reg -- guide-verified layouts).
// LDS: 2 buffers x 4 tiles (Xhi,Xlo,Ehi,Elo) of [128][32] bf16, 16B-granule
// swizzle slot = (q + (r>>1))&3  -> conflict-free writes, 2-way (free) reads.
// Per lane two-min tracking (v1,i1,v2) per row-slot; merged across 16 lanes.
// Rows with gap <= THRESH are flagged for exact recheck (ties give gap 0,
// so the first-index rule is always delegated to the exact path).
#define TBYTE(r_, q_) ((r_) * 64 + ((((q_) + ((r_) >> 1)) & 3) << 4))

__global__ __launch_bounds__(256) void k_pass1f(
    const float* __restrict__ X,
    const ushort* __restrict__ Xhi_g, const ushort* __restrict__ Xlo_g,
    const ushort* __restrict__ Ehi_g, const ushort* __restrict__ Elo_g,
    const float* __restrict__ B32g, float* __restrict__ Arr,
    int* __restrict__ idx32, int* __restrict__ flagcnt,
    int* __restrict__ flaglist)
{
    __shared__ __align__(16) char smB[65536];   // 2 x 32KB buffers
    float* smf = (float*)smB;

    const int tid = threadIdx.x;
    const int w   = tid >> 6;          // wave 0..3 -> rows w*32..w*32+31
    const int lane = tid & 63;
    const int q4  = lane >> 4;         // k-quarter
    const int l15 = lane & 15;
    const int rowbase = blockIdx.x * 128;
    const int ra0 = w * 32 + l15;      // A-frag rows (tile-local)
    const int ra1 = ra0 + 16;

    uint4 stg[8];

#define FLOAD(cbn, chn)                                                         \
    do {                                                                        \
        _Pragma("unroll")                                                       \
        for (int i_ = 0; i_ < 8; ++i_) {                                        \
            int g_ = tid + ((i_ & 1) << 8);                                     \
            int r_ = g_ >> 2, qq_ = g_ & 3;                                     \
            size_t off_ = (size_t)(chn) * 32 + qq_ * 8;                         \
            const ushort* src_;                                                 \
            if ((i_ >> 1) == 0)                                                 \
                src_ = Xhi_g + (size_t)(rowbase + r_) * DIM + off_;             \
            else if ((i_ >> 1) == 1)                                            \
                src_ = Xlo_g + (size_t)(rowbase + r_) * DIM + off_;             \
            else if ((i_ >> 1) == 2)                                            \
                src_ = Ehi_g + (size_t)((cbn) + r_) * DIM + off_;               \
            else                                                                \
                src_ = Elo_g + (size_t)((cbn) + r_) * DIM + off_;               \
            stg[i_] = *(const uint4*)src_;                                      \
        }                                                                       \
    } while (0)

#define FWRITE(b)                                                               \
    do {                                                                        \
        char* base_ = smB + (b) * 32768;                                        \
        _Pragma("unroll")                                                       \
        for (int i_ = 0; i_ < 8; ++i_) {                                        \
            int g_ = tid + ((i_ & 1) << 8);                                     \
            int r_ = g_ >> 2, qq_ = g_ & 3;                                     \
            *(uint4*)(base_ + (i_ >> 1) * 8192 + TBYTE(r_, qq_)) = stg[i_];     \
        }                                                                       \
    } while (0)

    // prologue: issue stage-0 loads early
    FLOAD(0, 0);

    // row norms (numpy halves) -> smf pairs; then a8 regs + Arr global
    {
        int r = tid >> 1, h = tid & 1;
        smf[(r << 1) + h] = half_sq_sum(X + (size_t)(rowbase + r) * DIM + (h << 7));
    }
    __syncthreads();
    float a8[8];
#pragma unroll
    for (int s = 0; s < 8; ++s) {
        int row = w * 32 + (s >> 2) * 16 + q4 * 4 + (s & 3);
        a8[s] = __fadd_rn(smf[row * 2], smf[row * 2 + 1]);
    }
    if (tid < 128)
        Arr[rowbase + tid] = __fadd_rn(smf[tid * 2], smf[tid * 2 + 1]);
    __syncthreads();
    FWRITE(0);

    float v1[8], v2[8]; int i1[8];
#pragma unroll
    for (int s = 0; s < 8; ++s) { v1[s] = 3.0e38f; v2[s] = 3.0e38f; i1[s] = 0; }

    int cur = 0;
    for (int cb = 0; cb < 8; ++cb) {
        f32x4 acc0[8], acc1[8];
#pragma unroll
        for (int cf = 0; cf < 8; ++cf) {
            acc0[cf] = (f32x4){0.f, 0.f, 0.f, 0.f};
            acc1[cf] = (f32x4){0.f, 0.f, 0.f, 0.f};
        }
        for (int ch = 0; ch < 8; ++ch) {
            const int s = cb * 8 + ch;
            __syncthreads();
            if (s < 63) { const int sn = s + 1; FLOAD((sn >> 3) * 128, (sn & 7)); }
            {
                const char* Xh = smB + cur * 32768;
                const char* Xl = Xh + 8192;
                const char* Eh = Xh + 16384;
                const char* El = Xh + 24576;
                bf16x8 ah0 = *(const bf16x8*)(Xh + TBYTE(ra0, q4));
                bf16x8 ah1 = *(const bf16x8*)(Xh + TBYTE(ra1, q4));
                bf16x8 al0 = *(const bf16x8*)(Xl + TBYTE(ra0, q4));
                bf16x8 al1 = *(const bf16x8*)(Xl + TBYTE(ra1, q4));
#pragma unroll
                for (int cf = 0; cf < 8; ++cf) {
                    int rc = cf * 16 + l15;
                    bf16x8 bh = *(const bf16x8*)(Eh + TBYTE(rc, q4));
                    bf16x8 bl = *(const bf16x8*)(El + TBYTE(rc, q4));
                    acc0[cf] = __builtin_amdgcn_mfma_f32_16x16x32_bf16(ah0, bh, acc0[cf], 0, 0, 0);
                    acc0[cf] = __builtin_amdgcn_mfma_f32_16x16x32_bf16(ah0, bl, acc0[cf], 0, 0, 0);
                    acc0[cf] = __builtin_amdgcn_mfma_f32_16x16x32_bf16(al0, bh, acc0[cf], 0, 0, 0);
                    acc1[cf] = __builtin_amdgcn_mfma_f32_16x16x32_bf16(ah1, bh, acc1[cf], 0, 0, 0);
                    acc1[cf] = __builtin_amdgcn_mfma_f32_16x16x32_bf16(ah1, bl, acc1[cf], 0, 0, 0);
                    acc1[cf] = __builtin_amdgcn_mfma_f32_16x16x32_bf16(al1, bh, acc1[cf], 0, 0, 0);
                }
            }
            if (s < 63) FWRITE(cur ^ 1);
            cur ^= 1;
        }
        // fold: approx dist + two-min update (dist formula matches recheck)
#pragma unroll
        for (int cf = 0; cf < 8; ++cf) {
            const int c = cb * 128 + cf * 16 + l15;
            const float b = B32g[c];
#pragma unroll
            for (int reg = 0; reg < 4; ++reg) {
                {
                    float dv = __fsub_rn(__fadd_rn(a8[reg], b),
                                         __fmul_rn(2.0f, acc0[cf][reg]));
                    if (dv < v1[reg]) { v2[reg] = v1[reg]; v1[reg] = dv; i1[reg] = c; }
                    else if (dv < v2[reg]) v2[reg] = dv;
                }
                {
                    float dv = __fsub_rn(__fadd_rn(a8[4 + reg], b),
                                         __fmul_rn(2.0f, acc1[cf][reg]));
                    if (dv < v1[4 + reg]) { v2[4 + reg] = v1[4 + reg]; v1[4 + reg] = dv; i1[4 + reg] = c; }
                    else if (dv < v2[4 + reg]) v2[4 + reg] = dv;
                }
            }
        }
    }

    // merge (v1,i1,v2) across the 16 lanes per row
    __syncthreads();
    float* Mv = (float*)smB;            // [128][16]
    int*   Mi = (int*)(smB + 8192);
    float* M2 = (float*)(smB + 16384);
#pragma unroll
    for (int s = 0; s < 8; ++s) {
        int row = w * 32 + (s >> 2) * 16 + q4 * 4 + (s & 3);
        Mv[row * 16 + l15] = v1[s];
        Mi[row * 16 + l15] = i1[s];
        M2[row * 16 + l15] = v2[s];
    }
    __syncthreads();
    if (tid < 128) {
        float bv1 = Mv[tid * 16]; int bi = Mi[tid * 16]; float bv2 = M2[tid * 16];
        for (int t = 1; t < 16; ++t) {
            float av1 = Mv[tid * 16 + t];
            int   ai  = Mi[tid * 16 + t];
            float av2 = M2[tid * 16 + t];
            if (av1 < bv1) { bv2 = fminf(bv1, av2); bv1 = av1; bi = ai; }
            else           { bv2 = fminf(bv2, av1); }
        }
        idx32[rowbase + tid] = bi;
        if (bv2 - bv1 <= THRESH) {
            int slot = atomicAdd(flagcnt, 1);
            flaglist[slot] = rowbase + tid;
        }
    }
#undef FLOAD
#undef FWRITE
}

// ---------------- P4: exact recheck of flagged rows ------------------------
// Reference-exact distances (single fma chain, d ascending, fl(fl(A+B)-2D))
// for all 1024 candidates of each flagged row; strict-< first-index argmin.
__global__ __launch_bounds__(256) void k_recheck(
    const float* __restrict__ X, const float* __restrict__ E,
    const float* __restrict__ B32, const float* __restrict__ Arr,
    const int* __restrict__ flaglist, const int* __restrict__ flagcnt,
    int* __restrict__ idx32)
{
    __shared__ float xr[256];
    __shared__ float Et[256 * 33];
    __shared__ float rv[256];
    __shared__ int   rc[256];
    const int tid = threadIdx.x;
    const int nf = *flagcnt;
    for (int f = blockIdx.x; f < nf; f += gridDim.x) {
        const int row = flaglist[f];
        __syncthreads();                       // protect LDS reuse across f
        xr[tid] = X[(size_t)row * DIM + tid];
        const float A = Arr[row];
        float bestv = 3.0e38f; int bestc = 0;
        for (int cp = 0; cp < 4; ++cp) {
            float acc = 0.0f;
            for (int dch = 0; dch < 8; ++dch) {
                __syncthreads();
#pragma unroll
                for (int i = 0; i < 8; ++i) {
                    int g = tid + i * 256;
                    int r = g >> 3, d4 = (g & 7) * 4;
                    float4 v = *(const float4*)(E + (size_t)(cp * 256 + r) * DIM
                                                + dch * 32 + d4);
                    Et[r * 33 + d4 + 0] = v.x; Et[r * 33 + d4 + 1] = v.y;
                    Et[r * 33 + d4 + 2] = v.z; Et[r * 33 + d4 + 3] = v.w;
                }
                __syncthreads();
#pragma unroll
                for (int dd = 0; dd < 32; ++dd)
                    acc = fmaf(xr[dch * 32 + dd], Et[tid * 33 + dd], acc);
            }
            const int c = cp * 256 + tid;
            float dv = __fsub_rn(__fadd_rn(A, B32[c]), __fmul_rn(2.0f, acc));
            if (dv < bestv) { bestv = dv; bestc = c; }
        }
        rv[tid] = bestv; rc[tid] = bestc;
        __syncthreads();
        for (int off = 128; off > 0; off >>= 1) {
            if (tid < off) {
                float av = rv[tid + off]; int ac = rc[tid + off];
                if (av < rv[tid] || (av == rv[tid] && ac < rc[tid])) {
                    rv[tid] = av; rc[tid] = ac;
                }
            }
            __syncthreads();
        }
        if (tid == 0) idx32[row] = rc[0];
    }
}

// ---------------- P5: gather quantized + fp64 loss -------------------------
__global__ __launch_bounds__(256) void k_out(
    const float* __restrict__ X, const float* __restrict__ E,
    const int* __restrict__ idx32, float* __restrict__ out0,
    double* __restrict__ lossacc)
{
    const int NF4 = NQ / 4;
    double s = 0.0;
    for (int g = blockIdx.x * blockDim.x + threadIdx.x; g < NF4;
         g += gridDim.x * blockDim.x) {
        int row = g >> 6;
        int d4  = g & 63;
        int j = idx32[row];
        float4 q = *(const float4*)(E + (size_t)j * DIM + d4 * 4);
        float4 x = *(const float4*)(X + (size_t)g * 4);
        *(float4*)(out0 + (size_t)g * 4) = q;
        double dx;
        dx = (double)q.x - (double)x.x; s = fma(dx, dx, s);
        dx = (double)q.y - (double)x.y; s = fma(dx, dx, s);
        dx = (double)q.z - (double)x.z; s = fma(dx, dx, s);
        dx = (double)q.w - (double)x.w; s = fma(dx, dx, s);
    }
#pragma unroll
    for (int off = 32; off > 0; off >>= 1) s += __shfl_down(s, off, 64);
    __shared__ double wsum[4];
    int lane = threadIdx.x & 63, wv = threadIdx.x >> 6;
    if (lane == 0) wsum[wv] = s;
    __syncthreads();
    if (threadIdx.x == 0) {
        double t = wsum[0] + wsum[1] + wsum[2] + wsum[3];
        atomicAdd(lossacc, t);
    }
}

// ---------------- P6: index output + histogram -----------------------------
__global__ __launch_bounds__(256) void k_idxout(
    const int* __restrict__ idx32, float* __restrict__ out1,
    int* __restrict__ counts)
{
    __shared__ int h[KC];
    for (int i = threadIdx.x; i < KC; i += 256) h[i] = 0;
    __syncthreads();
    int r = blockIdx.x * 256 + threadIdx.x;
    int j = idx32[r];
    out1[r] = (float)j;
    atomicAdd(&h[j], 1);
    __syncthreads();
    for (int i = threadIdx.x; i < KC; i += 256)
        if (h[i]) atomicAdd(&counts[i], h[i]);
}

// =================== FALLBACK PATH (R5 kernel, proven 518 us) ===============

__global__ __launch_bounds__(256) void k_prepB(const float* __restrict__ E,
                                               float* __restrict__ B32) {
    int j = blockIdx.x * 256 + threadIdx.x;
    if (j >= KC) return;
    B32[j] = sq_sum_numpy(E + (size_t)j * DIM);
}

#define TM 128
#define TN 128
#define TD 32
#define BUFF 4096
#define BSTR 8192

#define PKL(d_, x_, e_)                                                         \
    asm("v_pk_fma_f32 %0, %1, %2, %0 op_sel:[0,0,0] op_sel_hi:[0,1,1]"          \
        : "+v"(d_) : "v"(x_), "v"(e_));
#define PKH(d_, x_, e_)                                                         \
    asm("v_pk_fma_f32 %0, %1, %2, %0 op_sel:[1,0,0] op_sel_hi:[1,1,1]"          \
        : "+v"(d_) : "v"(x_), "v"(e_));

__global__ __launch_bounds__(256, 2) void k_pass1_fb(
    const float* __restrict__ X, const float* __restrict__ E,
    const float* __restrict__ B32, float* __restrict__ out0,
    float* __restrict__ out1, int* __restrict__ counts,
    double* __restrict__ lossacc)
{
    __shared__ __align__(16) float sm[2 * BSTR];

    const int tid = threadIdx.x;
    const int tx  = tid & 15;
    const int ty  = tid >> 4;
    const int rowbase = blockIdx.x * TM;

    float4 xv0, xv1, xv2, xv3, ev0, ev1, ev2, ev3;

#define LOADR(cbn, dcn)                                                         \
    do {                                                                        \
        int fi_, r_, d4_;                                                       \
        fi_ = tid;       r_ = fi_ >> 3; d4_ = (fi_ & 7) << 2;                   \
        xv0 = *(const float4*)(X + (size_t)(rowbase + r_) * DIM + (dcn) + d4_); \
        ev0 = *(const float4*)(E + (size_t)((cbn) + r_) * DIM + (dcn) + d4_);   \
        fi_ = tid + 256; r_ = fi_ >> 3; d4_ = (fi_ & 7) << 2;                   \
        xv1 = *(const float4*)(X + (size_t)(rowbase + r_) * DIM + (dcn) + d4_); \
        ev1 = *(const float4*)(E + (size_t)((cbn) + r_) * DIM + (dcn) + d4_);   \
        fi_ = tid + 512; r_ = fi_ >> 3; d4_ = (fi_ & 7) << 2;                   \
        xv2 = *(const float4*)(X + (size_t)(rowbase + r_) * DIM + (dcn) + d4_); \
        ev2 = *(const float4*)(E + (size_t)((cbn) + r_) * DIM + (dcn) + d4_);   \
        fi_ = tid + 768; r_ = fi_ >> 3; d4_ = (fi_ & 7) << 2;                   \
        xv3 = *(const float4*)(X + (size_t)(rowbase + r_) * DIM + (dcn) + d4_); \
        ev3 = *(const float4*)(E + (size_t)((cbn) + r_) * DIM + (dcn) + d4_);   \
    } while (0)

#define WRITE1(Xs_, Es_, v_, e_, fif_)                                          \
    do {                                                                        \
        int r_ = (fif_) >> 3, d4_ = ((fif_) & 7) << 2;                          \
        int off_ = d4_ * 128 + ((((r_) >> 2) ^ (d4_ >> 2)) << 2) + ((r_) & 3);  \
        (Xs_)[off_]       = v_.x; (Xs_)[off_ + 128] = v_.y;                     \
        (Xs_)[off_ + 256] = v_.z; (Xs_)[off_ + 384] = v_.w;                     \
        (Es_)[off_]       = e_.x; (Es_)[off_ + 128] = e_.y;                     \
        (Es_)[off_ + 256] = e_.z; (Es_)[off_ + 384] = e_.w;                     \
    } while (0)

#define WRITEB(b)                                                               \
    do {                                                                        \
        float* Xs_ = sm + (b) * BSTR;                                           \
        float* Es_ = Xs_ + BUFF;                                                \
        WRITE1(Xs_, Es_, xv0, ev0, tid);                                        \
        WRITE1(Xs_, Es_, xv1, ev1, tid + 256);                                  \
        WRITE1(Xs_, Es_, xv2, ev2, tid + 512);                                  \
        WRITE1(Xs_, Es_, xv3, ev3, tid + 768);                                  \
    } while (0)

    LOADR(0, 0);
    {
        int r = tid >> 1, h = tid & 1;
        sm[(r << 1) + h] = half_sq_sum(X + (size_t)(rowbase + r) * DIM + (h << 7));
    }
    __syncthreads();
    float a8[8];
#pragma unroll
    for (int i = 0; i < 8; ++i)
        a8[i] = __fadd_rn(sm[(ty * 8 + i) * 2], sm[(ty * 8 + i) * 2 + 1]);
    __syncthreads();
    WRITEB(0);

    float v1[8]; int i1[8];
#pragma unroll
    for (int i = 0; i < 8; ++i) { v1[i] = 3.0e38f; i1[i] = 0; }

    int cur = 0;
    for (int cb8 = 0; cb8 < 8; ++cb8) {
        const int cbase = cb8 * TN;
        f2 acc[8][4];
#pragma unroll
        for (int i = 0; i < 8; ++i)
#pragma unroll
            for (int j = 0; j < 4; ++j) acc[i][j] = (f2){0.0f, 0.0f};

        for (int dc8 = 0; dc8 < 8; ++dc8) {
            const int s = cb8 * 8 + dc8;
            __syncthreads();
            if (s < 63) {
                const int sn = s + 1;
                LOADR((sn >> 3) * TN, (sn & 7) * TD);
            }
            {
                const float* Xc = sm + cur * BSTR;
                const float* Ec = Xc + BUFF;
#pragma unroll 2
                for (int dq = 0; dq < 8; ++dq) {
                    const float* xp0 = Xc + dq * 512 + ((((ty << 1)    ) ^ dq) << 2);
                    const float* xp1 = Xc + dq * 512 + ((((ty << 1) | 1) ^ dq) << 2);
                    const float* ep0 = Ec + dq * 512 + ((tx ^ dq) << 2);
#pragma unroll
                    for (int ddi = 0; ddi < 4; ++ddi) {
                        f4v t0 = *(const f4v*)(xp0 + ddi * 128);
                        f4v t1 = *(const f4v*)(xp1 + ddi * 128);
                        f4v u0 = *(const f4v*)(ep0 + ddi * 128);
                        f4v u1 = *(const f4v*)(ep0 + ddi * 128 + 64);
                        f2 x01 = __builtin_shufflevector(t0, t0, 0, 1);
                        f2 x23 = __builtin_shufflevector(t0, t0, 2, 3);
                        f2 x45 = __builtin_shufflevector(t1, t1, 0, 1);
                        f2 x67 = __builtin_shufflevector(t1, t1, 2, 3);
                        f2 e0  = __builtin_shufflevector(u0, u0, 0, 1);
                        f2 e1  = __builtin_shufflevector(u0, u0, 2, 3);
                        f2 e2  = __builtin_shufflevector(u1, u1, 0, 1);
                        f2 e3  = __builtin_shufflevector(u1, u1, 2, 3);
                        PKL(acc[0][0], x01, e0) PKL(acc[0][1], x01, e1)
                        PKL(acc[0][2], x01, e2) PKL(acc[0][3], x01, e3)
                        PKH(acc[1][0], x01, e0) PKH(acc[1][1], x01, e1)
                        PKH(acc[1][2], x01, e2) PKH(acc[1][3], x01, e3)
                        PKL(acc[2][0], x23, e0) PKL(acc[2][1], x23, e1)
                        PKL(acc[2][2], x23, e2) PKL(acc[2][3], x23, e3)
                        PKH(acc[3][0], x23, e0) PKH(acc[3][1], x23, e1)
                        PKH(acc[3][2], x23, e2) PKH(acc[3][3], x23, e3)
                        PKL(acc[4][0], x45, e0) PKL(acc[4][1], x45, e1)
                        PKL(acc[4][2], x45, e2) PKL(acc[4][3], x45, e3)
                        PKH(acc[5][0], x45, e0) PKH(acc[5][1], x45, e1)
                        PKH(acc[5][2], x45, e2) PKH(acc[5][3], x45, e3)
                        PKL(acc[6][0], x67, e0) PKL(acc[6][1], x67, e1)
                        PKL(acc[6][2], x67, e2) PKL(acc[6][3], x67, e3)
                        PKH(acc[7][0], x67, e0) PKH(acc[7][1], x67, e1)
                        PKH(acc[7][2], x67, e2) PKH(acc[7][3], x67, e3)
                    }
                }
            }
            if (s < 63) WRITEB(cur ^ 1);
            cur ^= 1;
        }

        float4 bq0 = *(const float4*)(B32 + cbase + (tx << 2));
        float4 bq1 = *(const float4*)(B32 + cbase + 64 + (tx << 2));
        float bvv[8] = {bq0.x, bq0.y, bq0.z, bq0.w, bq1.x, bq1.y, bq1.z, bq1.w};
#pragma unroll
        for (int j = 0; j < 8; ++j) {
            const int c = cbase + ((j < 4) ? ((tx << 2) + j)
                                           : (64 + (tx << 2) + (j - 4)));
#pragma unroll
            for (int i = 0; i < 8; ++i) {
                float av  = acc[i][j >> 1][j & 1];
                float Cv  = __fmul_rn(2.0f, av);
                float t1v = __fadd_rn(a8[i], bvv[j]);
                float dv  = __fsub_rn(t1v, Cv);
                if (dv < v1[i]) { v1[i] = dv; i1[i] = c; }
            }
        }
    }

    __syncthreads();
    float* Mv   = sm;
    int*   Mi   = (int*)(sm + 2048);
    int*   sIdx = (int*)(sm + 4096);
    double* wsum = (double*)(sm + 4224);
#pragma unroll
    for (int i = 0; i < 8; ++i) {
        int r = ty * 8 + i;
        Mv[r * 16 + tx] = v1[i];
        Mi[r * 16 + tx] = i1[i];
    }
    __syncthreads();
    if (tid < TM) {
        int r = tid;
        float bv = Mv[r * 16];
        int   bi = Mi[r * 16];
        for (int t = 1; t < 16; ++t) {
            float av = Mv[r * 16 + t];
            int   ai = Mi[r * 16 + t];
            if (av < bv || (av == bv && ai < bi)) { bv = av; bi = ai; }
        }
        sIdx[r] = bi;
        out1[rowbase + r] = (float)bi;
        atomicAdd(&counts[bi], 1);
    }
    __syncthreads();

    const size_t base = (size_t)rowbase * DIM;
    double s = 0.0;
#pragma unroll 4
    for (int g = 0; g < 32; ++g) {
        int fi  = tid + g * 256;
        int row = fi >> 6;
        int d4  = fi & 63;
        int j = sIdx[row];
        float4 q = *(const float4*)(E + (size_t)j * DIM + d4 * 4);
        float4 x = *(const float4*)(X + base + (size_t)fi * 4);
        *(float4*)(out0 + base + (size_t)fi * 4) = q;
        double dx;
        dx = (double)q.x - (double)x.x; s = fma(dx, dx, s);
        dx = (double)q.y - (double)x.y; s = fma(dx, dx, s);
        dx = (double)q.z - (double)x.z; s = fma(dx, dx, s);
        dx = (double)q.w - (double)x.w; s = fma(dx, dx, s);
    }
#pragma unroll
    for (int off = 32; off > 0; off >>= 1) s += __shfl_down(s, off, 64);
    int lane = tid & 63, wv = tid >> 6;
    if (lane == 0) wsum[wv] = s;
    __syncthreads();
    if (tid == 0) {
        double t = wsum[0] + wsum[1] + wsum[2] + wsum[3];
        atomicAdd(lossacc, t);
    }
#undef LOADR
#undef WRITE1
#undef WRITEB
}

// ---------------- shared: perplexity + loss finalize -----------------------
__global__ void k_fin(const int* __restrict__ counts,
                      const double* __restrict__ lossacc,
                      float* __restrict__ out_pl)
{
    __shared__ double sh[256];
    double s = 0.0;
    for (int i = threadIdx.x; i < KC; i += 256) {
        double p = (double)counts[i] / 65536.0;
        s += p * log(p + 1.1920928955078125e-07);
    }
    sh[threadIdx.x] = s;
    __syncthreads();
    for (int off = 128; off > 0; off >>= 1) {
        if (threadIdx.x < off) sh[threadIdx.x] += sh[threadIdx.x + off];
        __syncthreads();
    }
    if (threadIdx.x == 0) {
        out_pl[0] = (float)exp(-sh[0]);
        out_pl[1] = (float)((*lossacc / (double)NQ) * 1.1);
    }
}

extern "C" void kernel_launch(void* const* d_in, const int* in_sizes, int n_in,
                              void* d_out, int out_size, void* d_ws, size_t ws_size,
                              hipStream_t stream) {
    const float* X = (const float*)d_in[0];
    const float* E = (const float*)d_in[1];
    float* out = (float*)d_out;
    char* ws = (char*)d_ws;

    double* lossacc = (double*)(ws + 0);
    int*    counts  = (int*)(ws + 16);
    float*  B32     = (float*)(ws + 4224);

    if (ws_size >= (size_t)WS_REQ) {
        // -------- fast path: bf16-split MFMA + exact recheck --------
        int*    flagcnt  = (int*)(ws + 8320);
        int*    flaglist = (int*)(ws + 16384);
        int*    idx32    = (int*)(ws + 278528);
        float*  Arr      = (float*)(ws + 540672);
        ushort* Ehi      = (ushort*)(ws + 802816);
        ushort* Elo      = (ushort*)(ws + 1327104);
        ushort* Xhi      = (ushort*)out;            // out0 as scratch
        ushort* Xlo      = Xhi + (size_t)NQ;        // overwritten by k_out

        hipMemsetAsync(d_ws, 0, 8336, stream);
        hipLaunchKernelGGL(k_prepE, dim3(4),    dim3(256), 0, stream, E, B32, Ehi, Elo);
        hipLaunchKernelGGL(k_prepX, dim3(8192), dim3(256), 0, stream, X, Xhi, Xlo);
        hipLaunchKernelGGL(k_pass1f, dim3(512), dim3(256), 0, stream,
                           X, Xhi, Xlo, Ehi, Elo, B32, Arr, idx32, flagcnt, flaglist);
        hipLaunchKernelGGL(k_recheck, dim3(2048), dim3(256), 0, stream,
                           X, E, B32, Arr, flaglist, flagcnt, idx32);
        hipLaunchKernelGGL(k_out,    dim3(2048), dim3(256), 0, stream,
                           X, E, idx32, out, lossacc);
        hipLaunchKernelGGL(k_idxout, dim3(256),  dim3(256), 0, stream,
                           idx32, out + NQ, counts);
        hipLaunchKernelGGL(k_fin,    dim3(1),    dim3(256), 0, stream,
                           counts, lossacc, out + NQ + 65536);
    } else {
        // -------- fallback: proven R5 path --------
        hipMemsetAsync(d_ws, 0, 4224, stream);
        hipLaunchKernelGGL(k_prepB, dim3(4),          dim3(256), 0, stream, E, B32);
        hipLaunchKernelGGL(k_pass1_fb, dim3(ROWS / TM), dim3(256), 0, stream,
                           X, E, B32, out, out + NQ, counts, lossacc);
        hipLaunchKernelGGL(k_fin,   dim3(1),          dim3(256), 0, stream,
                           counts, lossacc, out + NQ + 65536);
    }
}